// Round 1
// baseline (138.914 us; speedup 1.0000x reference)
//
#include <hip/hip_runtime.h>
#include <hip/hip_bf16.h>

#define N_N 128
#define N_C 7
#define N_H 96
#define N_W 192
#define HW (N_H * N_W)            // 18432
#define CHW (N_C * HW)            // 129024
#define NHW (N_N * HW)            // 2359296  (bg element count)
#define NPTS 100
#define NK (N_N * N_C)            // 896
#define NPAIR (NPTS * NPTS)       // 10000
#define BG_BLOCKS 1024
#define SIGMA_F 2.0f

// ---------------- kernel 1: BCE-with-logits partial sums over channel 0 ----
__global__ void bg_kernel(const float* __restrict__ in,
                          const float* __restrict__ tg,
                          double* __restrict__ partial) {
    const int tid = blockIdx.x * blockDim.x + threadIdx.x;
    const int nthreads = gridDim.x * blockDim.x;
    const int NV = NHW / 4;               // 589824 float4 elements
    const int HV = HW / 4;                // 4608 float4 per image (channel 0)
    const int CV = CHW / 4;               // 32256 float4 stride per n
    const float4* in4 = (const float4*)in;
    const float4* tg4 = (const float4*)tg;
    float s = 0.0f;
    for (int e = tid; e < NV; e += nthreads) {
        int n = e / HV;
        int r = e - n * HV;
        float4 x4 = in4[n * CV + r];
        float4 t4 = tg4[n * CV + r];
        const float* xp = &x4.x;
        const float* tp = &t4.x;
#pragma unroll
        for (int q = 0; q < 4; ++q) {
            float x = xp[q], t = tp[q];
            s += fmaxf(x, 0.0f) - x * t + log1pf(expf(-fabsf(x)));
        }
    }
    __shared__ float sdata[256];
    sdata[threadIdx.x] = s;
    __syncthreads();
    for (int off = 128; off > 0; off >>= 1) {
        if (threadIdx.x < off) sdata[threadIdx.x] += sdata[threadIdx.x + off];
        __syncthreads();
    }
    if (threadIdx.x == 0) partial[blockIdx.x] = (double)sdata[0];
}

// ---------------- kernel 2: gather P, G ------------------------------------
__global__ void gather_kernel(const float* __restrict__ in,
                              const float* __restrict__ tg,
                              const int* __restrict__ px,
                              const int* __restrict__ py,
                              float* __restrict__ P,
                              float* __restrict__ G) {
    int idx = blockIdx.x * blockDim.x + threadIdx.x;   // over NK*NPTS = 89600
    if (idx >= NK * NPTS) return;
    int k = idx / NPTS;          // 0..895  (n*7+c)
    int i = idx - k * NPTS;      // 0..99
    int n = k / N_C;
    int c = k - n * N_C;
    int off = n * CHW + c * HW + py[i] * N_W + px[i];
    P[idx] = in[off];
    G[idx] = tg[off];
}

// ---------------- kernel 3: term1[i] = sum_k xlogy(P) ----------------------
__global__ void term1_kernel(const float* __restrict__ P,
                             float* __restrict__ term1) {
    int i = blockIdx.x;          // 0..99
    float s = 0.0f;
    for (int k = threadIdx.x; k < NK; k += blockDim.x) {
        float p = P[k * NPTS + i];
        s += (p > 0.0f) ? p * logf(p) : 0.0f;
    }
    __shared__ float sdata[128];
    sdata[threadIdx.x] = s;
    __syncthreads();
    for (int off = 64; off > 0; off >>= 1) {
        if (threadIdx.x < off) sdata[threadIdx.x] += sdata[threadIdx.x + off];
        __syncthreads();
    }
    if (threadIdx.x == 0) term1[i] = sdata[0];
}

// ---------------- kernel 4: one wave per (i,j) pair ------------------------
__global__ void pairs_kernel(const float* __restrict__ P,
                             const float* __restrict__ G,
                             const float* __restrict__ term1,
                             const int* __restrict__ px,
                             const int* __restrict__ py,
                             float* __restrict__ pairL) {
    int wave = (blockIdx.x * blockDim.x + threadIdx.x) >> 6;
    int lane = threadIdx.x & 63;
    if (wave >= NPAIR) return;
    int i = wave / NPTS;
    int j = wave - i * NPTS;
    float cross = 0.0f;
    int eqf = 1;
#pragma unroll
    for (int k = lane; k < NK; k += 64) {   // 896/64 = 14 iterations exactly
        float pi = P[k * NPTS + i];
        float pj = P[k * NPTS + j];
        cross = fmaf(pi, pj, cross);
        eqf &= (G[k * NPTS + i] == G[k * NPTS + j]);
    }
#pragma unroll
    for (int m = 32; m >= 1; m >>= 1) cross += __shfl_xor(cross, m);
    int alleq = __all(eqf);
    if (lane == 0) {
        float Dij = (term1[j] - cross) * (1.0f / (float)N_N);
        float Dji = (term1[i] - cross) * (1.0f / (float)N_N);
        float L;
        if (alleq) {
            L = Dij + Dji;
        } else {
            L = (float)(N_N * N_C) *
                (fmaxf(SIGMA_F - Dij, 0.0f) + fmaxf(SIGMA_F - Dji, 0.0f));
        }
        bool mask = (i != j) && (px[i] != px[j]) && (py[i] != py[j]);
        pairL[wave] = mask ? L : 0.0f;
    }
}

// ---------------- kernel 5: final reduction --------------------------------
__global__ void final_kernel(const double* __restrict__ bgpart,
                             const float* __restrict__ pairL,
                             const int* __restrict__ px,
                             const int* __restrict__ py,
                             float* __restrict__ out) {
    __shared__ double sdata[256];
    __shared__ int scnt[256];
    __shared__ int spx[NPTS], spy[NPTS];
    int t = threadIdx.x;
    if (t < NPTS) { spx[t] = px[t]; spy[t] = py[t]; }
    __syncthreads();

    // bg sum
    double s = 0.0;
    for (int b = t; b < BG_BLOCKS; b += 256) s += bgpart[b];
    sdata[t] = s;
    __syncthreads();
    for (int off = 128; off > 0; off >>= 1) {
        if (t < off) sdata[t] += sdata[t + off];
        __syncthreads();
    }
    double bg_sum = sdata[0];
    __syncthreads();

    // kl sum + cnt
    double kl = 0.0;
    int cnt = 0;
    for (int p = t; p < NPAIR; p += 256) {
        kl += (double)pairL[p];
        int i = p / NPTS;
        int j = p - i * NPTS;
        cnt += ((i != j) && (spx[i] != spx[j]) && (spy[i] != spy[j])) ? 1 : 0;
    }
    sdata[t] = kl;
    scnt[t] = cnt;
    __syncthreads();
    for (int off = 128; off > 0; off >>= 1) {
        if (t < off) { sdata[t] += sdata[t + off]; scnt[t] += scnt[t + off]; }
        __syncthreads();
    }
    if (t == 0) {
        double bg_loss = bg_sum / (double)NHW;
        double kl_loss = sdata[0] / (double)scnt[0];
        out[0] = (float)(bg_loss + kl_loss);
    }
}

// ---------------- launch ---------------------------------------------------
extern "C" void kernel_launch(void* const* d_in, const int* in_sizes, int n_in,
                              void* d_out, int out_size, void* d_ws, size_t ws_size,
                              hipStream_t stream) {
    const float* inputs  = (const float*)d_in[0];
    const float* targets = (const float*)d_in[1];
    const int*   px      = (const int*)d_in[2];
    const int*   py      = (const int*)d_in[3];
    float* out = (float*)d_out;

    // workspace layout (bytes)
    char* ws = (char*)d_ws;
    double* bgpart = (double*)ws;                       // 1024 * 8   = 8192
    float*  P      = (float*)(ws + 8192);               // 89600 * 4  = 358400
    float*  G      = (float*)(ws + 8192 + 358400);      // 89600 * 4  = 358400
    float*  term1  = (float*)(ws + 8192 + 2 * 358400);  // 100 * 4 (pad 512)
    float*  pairL  = (float*)(ws + 8192 + 2 * 358400 + 512); // 10000 * 4

    bg_kernel<<<BG_BLOCKS, 256, 0, stream>>>(inputs, targets, bgpart);
    gather_kernel<<<(NK * NPTS + 255) / 256, 256, 0, stream>>>(
        inputs, targets, px, py, P, G);
    term1_kernel<<<NPTS, 128, 0, stream>>>(P, term1);
    pairs_kernel<<<(NPAIR * 64 + 255) / 256, 256, 0, stream>>>(
        P, G, term1, px, py, pairL);
    final_kernel<<<1, 256, 0, stream>>>(bgpart, pairL, px, py, out);
}

// Round 2
// 45.210 us; speedup vs baseline: 3.0726x; 3.0726x over previous
//
#include <hip/hip_runtime.h>
#include <hip/hip_bf16.h>

#define N_N 128
#define N_C 7
#define N_H 96
#define N_W 192
#define HW (N_H * N_W)            // 18432
#define CHW (N_C * HW)            // 129024
#define NHW (N_N * HW)            // 2359296
#define NPTS 100
#define NK (N_N * N_C)            // 896
#define NK2 (NK / 2)              // 448 float2 per row
#define BG_BLOCKS 1024
#define PAIR_BLOCKS 400           // 4 blocks per i
#define SIGMA_F 2.0f

// ---------------- kernel A: bg partials (blocks 0..1023) + gather/transpose/
// term1 (blocks 1024..1123). Branch is uniform per block. --------------------
__global__ __launch_bounds__(256) void fusedA_kernel(
        const float* __restrict__ in, const float* __restrict__ tg,
        const int* __restrict__ px, const int* __restrict__ py,
        double* __restrict__ bgpart,        // [1024]
        float* __restrict__ Pt,             // [100][896]
        float* __restrict__ Gt,             // [100][896]
        float* __restrict__ term1) {        // [100]
    __shared__ float sdata[256];
    const int b = blockIdx.x;
    const int t = threadIdx.x;

    if (b < BG_BLOCKS) {
        // BCE-with-logits over channel 0, float4 vectorized
        const int NV = NHW / 4;               // 589824
        const int HV = HW / 4;                // 4608
        const int CV = CHW / 4;               // 32256
        const float4* in4 = (const float4*)in;
        const float4* tg4 = (const float4*)tg;
        float s = 0.0f;
        for (int e = b * 256 + t; e < NV; e += BG_BLOCKS * 256) {
            int n = e / HV;
            int r = e - n * HV;
            float4 x4 = in4[n * CV + r];
            float4 t4 = tg4[n * CV + r];
            const float* xp = &x4.x;
            const float* tp = &t4.x;
#pragma unroll
            for (int q = 0; q < 4; ++q) {
                float x = xp[q], tt = tp[q];
                s += fmaxf(x, 0.0f) - x * tt + log1pf(expf(-fabsf(x)));
            }
        }
        sdata[t] = s;
        __syncthreads();
        for (int off = 128; off > 0; off >>= 1) {
            if (t < off) sdata[t] += sdata[t + off];
            __syncthreads();
        }
        if (t == 0) bgpart[b] = (double)sdata[0];
    } else {
        // gather row i (transposed layout) + term1[i]
        const int i = b - BG_BLOCKS;          // 0..99
        const int base = py[i] * N_W + px[i];
        float s = 0.0f;
        for (int k = t; k < NK; k += 256) {
            int n = k / N_C;
            int c = k - n * N_C;
            int off = n * CHW + c * HW + base;
            float p = in[off];
            float g = tg[off];
            Pt[i * NK + k] = p;
            Gt[i * NK + k] = g;
            s += (p > 0.0f) ? p * logf(p) : 0.0f;
        }
        sdata[t] = s;
        __syncthreads();
        for (int off = 128; off > 0; off >>= 1) {
            if (t < off) sdata[t] += sdata[t + off];
            __syncthreads();
        }
        if (t == 0) term1[i] = sdata[0];
    }
}

// ---------------- kernel B: pairs. Block b -> i = b>>2, j in 25-wide slice. -
__global__ __launch_bounds__(256) void pairs_kernel(
        const float* __restrict__ Pt, const float* __restrict__ Gt,
        const float* __restrict__ term1,
        const int* __restrict__ px, const int* __restrict__ py,
        double* __restrict__ klpart) {       // [400]
    __shared__ float2 sP[NK2];
    __shared__ float2 sG[NK2];
    __shared__ double skl[4];
    const int b = blockIdx.x;
    const int i = b >> 2;
    const int jbase = (b & 3) * 25;
    const int t = threadIdx.x;
    const float2* Pt2 = (const float2*)Pt;
    const float2* Gt2 = (const float2*)Gt;

    // stage row i in LDS (coalesced float2)
    for (int q = t; q < NK2; q += 256) {
        sP[q] = Pt2[i * NK2 + q];
        sG[q] = Gt2[i * NK2 + q];
    }
    __syncthreads();

    const int w = t >> 6;
    const int lane = t & 63;
    const float t1i = term1[i];
    const int pxi = px[i], pyi = py[i];
    double kl = 0.0;

    for (int j = jbase + w; j < jbase + 25; j += 4) {
        float cross = 0.0f;
        int eqf = 1;
#pragma unroll
        for (int it = 0; it < 7; ++it) {      // 448 float2 / 64 lanes
            int q = lane + it * 64;
            float2 pj = Pt2[j * NK2 + q];
            float2 gj = Gt2[j * NK2 + q];
            float2 pi = sP[q];
            float2 gi = sG[q];
            cross = fmaf(pi.x, pj.x, cross);
            cross = fmaf(pi.y, pj.y, cross);
            eqf &= (gi.x == gj.x) & (gi.y == gj.y);
        }
#pragma unroll
        for (int m = 32; m >= 1; m >>= 1) cross += __shfl_xor(cross, m);
        int alleq = __all(eqf);
        if (lane == 0) {
            float Dij = (term1[j] - cross) * (1.0f / (float)N_N);
            float Dji = (t1i - cross) * (1.0f / (float)N_N);
            float L = alleq ? (Dij + Dji)
                            : (float)(N_N * N_C) *
                              (fmaxf(SIGMA_F - Dij, 0.0f) + fmaxf(SIGMA_F - Dji, 0.0f));
            bool mask = (i != j) && (pxi != px[j]) && (pyi != py[j]);
            if (mask) kl += (double)L;
        }
    }

    if (lane == 0) skl[w] = kl;
    __syncthreads();
    if (t == 0) klpart[b] = skl[0] + skl[1] + skl[2] + skl[3];
}

// ---------------- kernel C: final scalar -----------------------------------
__global__ __launch_bounds__(256) void final_kernel(
        const double* __restrict__ bgpart,   // [1024]
        const double* __restrict__ klpart,   // [400]
        const int* __restrict__ px, const int* __restrict__ py,
        float* __restrict__ out) {
    __shared__ double sdata[256];
    __shared__ int scnt[256];
    __shared__ int spx[NPTS], spy[NPTS];
    const int t = threadIdx.x;
    if (t < NPTS) { spx[t] = px[t]; spy[t] = py[t]; }
    __syncthreads();

    double s = 0.0;
    for (int q = t; q < BG_BLOCKS; q += 256) s += bgpart[q];
    double kl = 0.0;
    for (int q = t; q < PAIR_BLOCKS; q += 256) kl += klpart[q];
    int cnt = 0;
    for (int p = t; p < NPTS * NPTS; p += 256) {
        int i = p / NPTS;
        int j = p - i * NPTS;
        cnt += ((i != j) && (spx[i] != spx[j]) && (spy[i] != spy[j])) ? 1 : 0;
    }
    sdata[t] = s;
    __syncthreads();
    for (int off = 128; off > 0; off >>= 1) {
        if (t < off) sdata[t] += sdata[t + off];
        __syncthreads();
    }
    double bg_sum = sdata[0];
    __syncthreads();
    sdata[t] = kl;
    scnt[t] = cnt;
    __syncthreads();
    for (int off = 128; off > 0; off >>= 1) {
        if (t < off) { sdata[t] += sdata[t + off]; scnt[t] += scnt[t + off]; }
        __syncthreads();
    }
    if (t == 0) {
        double bg_loss = bg_sum / (double)NHW;
        double kl_loss = sdata[0] / (double)scnt[0];
        out[0] = (float)(bg_loss + kl_loss);
    }
}

// ---------------- launch ---------------------------------------------------
extern "C" void kernel_launch(void* const* d_in, const int* in_sizes, int n_in,
                              void* d_out, int out_size, void* d_ws, size_t ws_size,
                              hipStream_t stream) {
    const float* inputs  = (const float*)d_in[0];
    const float* targets = (const float*)d_in[1];
    const int*   px      = (const int*)d_in[2];
    const int*   py      = (const int*)d_in[3];
    float* out = (float*)d_out;

    char* ws = (char*)d_ws;
    double* bgpart = (double*)ws;                              // 1024*8 = 8192
    float*  Pt     = (float*)(ws + 8192);                      // 358400
    float*  Gt     = (float*)(ws + 8192 + 358400);             // 358400
    float*  term1  = (float*)(ws + 8192 + 2 * 358400);         // 512 (pad)
    double* klpart = (double*)(ws + 8192 + 2 * 358400 + 512);  // 400*8 = 3200

    fusedA_kernel<<<BG_BLOCKS + NPTS, 256, 0, stream>>>(
        inputs, targets, px, py, bgpart, Pt, Gt, term1);
    pairs_kernel<<<PAIR_BLOCKS, 256, 0, stream>>>(
        Pt, Gt, term1, px, py, klpart);
    final_kernel<<<1, 256, 0, stream>>>(bgpart, klpart, px, py, out);
}